// Round 8
// baseline (396.845 us; speedup 1.0000x reference)
//
#include <hip/hip_runtime.h>
#include <math.h>

typedef __attribute__((ext_vector_type(8))) short bf16x8;
typedef __attribute__((ext_vector_type(4))) float f32x4;
typedef __attribute__((ext_vector_type(2))) float f32x2;

static inline size_t align256(size_t x) { return (x + 255) & ~(size_t)255; }

__device__ inline ushort f2bf(float f) {
    uint u = __float_as_uint(f);
    u = (u + 0x7fffu + ((u >> 16) & 1u)) >> 16;
    return (ushort)u;
}
__device__ inline float bf2f(ushort b) { return __uint_as_float(((uint)b) << 16); }

// ---- manual OCP e4m3fn encode (|x| <= 448) ----
__device__ inline uint f2fp8(float x) {
    float ax = fabsf(x);
    uint s = (__float_as_uint(x) >> 31) << 7;
    if (ax < 0.015625f) {
        int q = (int)rintf(ax * 512.f);
        if (q == 8) return s | 0x08u;
        return s | (uint)q;
    }
    uint u = __float_as_uint(ax);
    u += 0x7ffffu + ((u >> 20) & 1u);
    int e8 = (int)(u >> 23) - 127;
    uint m = (u >> 20) & 7u;
    return s | ((uint)(e8 + 7) << 3) | m;
}

#if __has_builtin(__builtin_amdgcn_cvt_pk_f32_fp8)
__device__ inline float fp8dot16(uint4 qa, uint4 qb) {
    uint ua[4] = {qa.x, qa.y, qa.z, qa.w};
    uint ub[4] = {qb.x, qb.y, qb.z, qb.w};
    float s = 0.f;
    #pragma unroll
    for (int i = 0; i < 4; i++) {
        f32x2 a0 = __builtin_amdgcn_cvt_pk_f32_fp8(ua[i], false);
        f32x2 a1 = __builtin_amdgcn_cvt_pk_f32_fp8(ua[i], true);
        f32x2 b0 = __builtin_amdgcn_cvt_pk_f32_fp8(ub[i], false);
        f32x2 b1 = __builtin_amdgcn_cvt_pk_f32_fp8(ub[i], true);
        s += a0.x * b0.x + a0.y * b0.y + a1.x * b1.x + a1.y * b1.y;
    }
    return s;
}
#else
__device__ inline float fp8dec(uint b) {
    uint s = (b >> 7) & 1u, e = (b >> 3) & 0xfu, m = b & 7u;
    float dn = (float)(int)m * 0.001953125f;
    float nf = __uint_as_float((s << 31) | ((e + 120u) << 23) | (m << 20));
    float dv = s ? -dn : dn;
    return e ? nf : dv;
}
__device__ inline float fp8dot16(uint4 qa, uint4 qb) {
    uint ua[4] = {qa.x, qa.y, qa.z, qa.w};
    uint ub[4] = {qb.x, qb.y, qb.z, qb.w};
    float s = 0.f;
    #pragma unroll
    for (int i = 0; i < 4; i++)
        #pragma unroll
        for (int j = 0; j < 4; j++)
            s += fp8dec((ua[i] >> (8 * j)) & 0xffu) * fp8dec((ub[i] >> (8 * j)) & 0xffu);
    return s;
}
#endif

__device__ inline void fma8(float* acc, uint4 q, float s) {
    acc[0] += s * bf2f((ushort)(q.x & 0xffff)); acc[1] += s * bf2f((ushort)(q.x >> 16));
    acc[2] += s * bf2f((ushort)(q.y & 0xffff)); acc[3] += s * bf2f((ushort)(q.y >> 16));
    acc[4] += s * bf2f((ushort)(q.z & 0xffff)); acc[5] += s * bf2f((ushort)(q.z >> 16));
    acc[6] += s * bf2f((ushort)(q.w & 0xffff)); acc[7] += s * bf2f((ushort)(q.w >> 16));
}

// ---------- prep: count atomics + weight conversions + sim prefetch + ticket ----------
__global__ void prep_kernel(const int* __restrict__ e_col, int E, int* __restrict__ cnt,
                            const float* __restrict__ W1, const float* __restrict__ W2,
                            const float* __restrict__ Wy,
                            ushort* __restrict__ W1t, ushort* __restrict__ W2t,
                            ushort* __restrict__ WyTb, int H, int* __restrict__ ticket,
                            const int* __restrict__ pos_e, const float* __restrict__ sim,
                            float* __restrict__ simv, int N) {
    int i = blockIdx.x * blockDim.x + threadIdx.x;
    int HH = H * H;
    if (i == 0) *ticket = 0;
    if (i < E) {
        atomicAdd(&cnt[e_col[i]], 1);
    } else if (i < E + HH) {
        int j = i - E; int k = j / H, n = j % H;
        W1t[(size_t)n * H + k] = f2bf(W1[j]);
    } else if (i < E + 2 * HH) {
        int j = i - E - HH; int k = j / H, n = j % H;
        W2t[(size_t)n * H + k] = f2bf(W2[j]);
    } else if (i < E + 2 * HH + 64 * H) {
        int j = i - E - 2 * HH; int n = j / H, k = j % H;
        WyTb[j] = (n < 40) ? f2bf(Wy[(size_t)k * 40 + n]) : (ushort)0;
    } else if (i < E + 2 * HH + 64 * H + E) {
        int ei = i - (E + 2 * HH + 64 * H);
        int a = pos_e[ei], b = pos_e[E + ei];
        if (a < b) simv[ei] = sim[(size_t)a * N + b];
    }
}

// ---------- parallel scan (1024 threads, N = 16384) + dinv ----------
__global__ __launch_bounds__(1024) void scan_offsets(const int* __restrict__ cnt,
                                                     int* __restrict__ offsets,
                                                     int* __restrict__ fillpos,
                                                     float* __restrict__ dinv, int N) {
    __shared__ int wsum[16];
    int t = threadIdx.x;
    int lane = t & 63, w = t >> 6;
    int i0 = t * 16;
    int cl[16];
    #pragma unroll
    for (int j = 0; j < 4; j++) {
        int4 c = *(const int4*)(cnt + i0 + j * 4);
        cl[j * 4 + 0] = c.x; cl[j * 4 + 1] = c.y; cl[j * 4 + 2] = c.z; cl[j * 4 + 3] = c.w;
    }
    int s = 0;
    #pragma unroll
    for (int j = 0; j < 16; j++) s += cl[j];
    int x = s;
    #pragma unroll
    for (int o = 1; o < 64; o <<= 1) { int y = __shfl_up(x, o); if (lane >= o) x += y; }
    if (lane == 63) wsum[w] = x;
    __syncthreads();
    if (w == 0 && lane < 16) {
        int v = wsum[lane];
        #pragma unroll
        for (int o = 1; o < 16; o <<= 1) { int y = __shfl_up(v, o); if (lane >= o) v += y; }
        wsum[lane] = v;
    }
    __syncthreads();
    int wbase = (w == 0) ? 0 : wsum[w - 1];
    int off = wbase + x - s;
    #pragma unroll
    for (int j = 0; j < 16; j++) {
        int i = i0 + j;
        offsets[i] = off;
        fillpos[i] = off;
        dinv[i] = rsqrtf((float)(cl[j] + 1));
        off += cl[j];
    }
    if (t == 1023) offsets[N] = off;
}

// ---------- merged: gemm1 (blocks 0..255) + fill_csr (blocks 256..) ----------
__global__ __launch_bounds__(256) void fillgemm1_kernel(const float* __restrict__ feat,
                                                        const ushort* __restrict__ W1t,
                                                        ushort* __restrict__ xw1,
                                                        const int* __restrict__ e_row,
                                                        const int* __restrict__ e_col, int E,
                                                        int* __restrict__ fillpos,
                                                        int* __restrict__ csr_src, int NGB) {
    __shared__ ushort As[128][40];
    __shared__ ushort Bs[128][40];
    int b = blockIdx.x;
    int t = threadIdx.x;

    if (b >= NGB) {
        int e = (b - NGB) * 256 + t;
        if (e < E) {
            int p = atomicAdd(&fillpos[e_col[e]], 1);
            csr_src[p] = e_row[e];
        }
        return;
    }

    const int K = 256;
    int lane = t & 63, w = t >> 6;
    int wm = w >> 1, wn = w & 1;
    int brow = (b >> 1) * 128, bcol = (b & 1) * 128;
    int l15 = lane & 15, l4 = lane >> 4;

    f32x4 acc[4][4];
    for (int i = 0; i < 4; i++)
        for (int j = 0; j < 4; j++) { f32x4 z = {0.f, 0.f, 0.f, 0.f}; acc[i][j] = z; }

    for (int k0 = 0; k0 < K; k0 += 32) {
        #pragma unroll
        for (int i = 0; i < 2; i++) {
            int idx = t + i * 256;
            int r = idx >> 2, seg = idx & 3;
            const float* ap = feat + (size_t)(brow + r) * K + k0 + seg * 8;
            float4 f0 = *(const float4*)ap;
            float4 f1 = *(const float4*)(ap + 4);
            uint4 va;
            va.x = f2bf(f0.x) | ((uint)f2bf(f0.y) << 16);
            va.y = f2bf(f0.z) | ((uint)f2bf(f0.w) << 16);
            va.z = f2bf(f1.x) | ((uint)f2bf(f1.y) << 16);
            va.w = f2bf(f1.z) | ((uint)f2bf(f1.w) << 16);
            *(uint4*)&As[r][seg * 8] = va;
            *(uint4*)&Bs[r][seg * 8] = *(const uint4*)(W1t + (size_t)(bcol + r) * K + k0 + seg * 8);
        }
        __syncthreads();
        bf16x8 af[4], bfr[4];
        #pragma unroll
        for (int mf = 0; mf < 4; mf++)
            af[mf] = *(const bf16x8*)&As[wm * 64 + mf * 16 + l15][l4 * 8];
        #pragma unroll
        for (int nf = 0; nf < 4; nf++)
            bfr[nf] = *(const bf16x8*)&Bs[wn * 64 + nf * 16 + l15][l4 * 8];
        #pragma unroll
        for (int mf = 0; mf < 4; mf++)
            #pragma unroll
            for (int nf = 0; nf < 4; nf++)
                acc[mf][nf] = __builtin_amdgcn_mfma_f32_16x16x32_bf16(af[mf], bfr[nf], acc[mf][nf], 0, 0, 0);
        __syncthreads();
    }

    #pragma unroll
    for (int mf = 0; mf < 4; mf++)
        #pragma unroll
        for (int nf = 0; nf < 4; nf++)
            #pragma unroll
            for (int j = 0; j < 4; j++) {
                int r = brow + wm * 64 + mf * 16 + l4 * 4 + j;
                int c = bcol + wn * 64 + nf * 16 + l15;
                xw1[(size_t)r * 256 + c] = f2bf(acc[mf][nf][j]);
            }
}

// ---------- fused conv2: agg1(xw1)+relu -> LDS h1 tile -> GEMM2 -> xw2 ----------
__global__ __launch_bounds__(256) void conv2_fused_kernel(const ushort* __restrict__ xw1,
                                                          const float* __restrict__ dinv,
                                                          const int* __restrict__ offsets,
                                                          const int* __restrict__ csr_src,
                                                          const float* __restrict__ b1,
                                                          const ushort* __restrict__ W2t,
                                                          ushort* __restrict__ xw2, int N) {
    __shared__ ushort h1s[64][264];   // 33.8 KB (pad: 528B stride -> 2-way bank alias, free)
    __shared__ ushort Bs[256][40];    // 20.5 KB
    int t = threadIdx.x;
    int brow = blockIdx.x * 64;
    int l = t & 31;
    int grp = t >> 5;

    // phase A: aggregate 64 h1 rows into LDS
    for (int pass = 0; pass < 8; pass++) {
        int v = brow + pass * 8 + grp;
        float dv = dinv[v];
        float acc[8] = {0, 0, 0, 0, 0, 0, 0, 0};
        uint4 q = *(const uint4*)(xw1 + (size_t)v * 256 + l * 8);
        fma8(acc, q, dv * dv);
        int beg = offsets[v], end = offsets[v + 1];
        int e = beg;
        for (; e + 2 <= end; e += 2) {
            int r0 = csr_src[e], r1 = csr_src[e + 1];
            float n0 = dinv[r0] * dv, n1 = dinv[r1] * dv;
            uint4 p0 = *(const uint4*)(xw1 + (size_t)r0 * 256 + l * 8);
            uint4 p1 = *(const uint4*)(xw1 + (size_t)r1 * 256 + l * 8);
            fma8(acc, p0, n0); fma8(acc, p1, n1);
        }
        if (e < end) {
            int r0 = csr_src[e];
            uint4 p0 = *(const uint4*)(xw1 + (size_t)r0 * 256 + l * 8);
            fma8(acc, p0, dinv[r0] * dv);
        }
        float4 bb0 = *(const float4*)(b1 + l * 8);
        float4 bb1 = *(const float4*)(b1 + l * 8 + 4);
        acc[0] = fmaxf(acc[0] + bb0.x, 0.f); acc[1] = fmaxf(acc[1] + bb0.y, 0.f);
        acc[2] = fmaxf(acc[2] + bb0.z, 0.f); acc[3] = fmaxf(acc[3] + bb0.w, 0.f);
        acc[4] = fmaxf(acc[4] + bb1.x, 0.f); acc[5] = fmaxf(acc[5] + bb1.y, 0.f);
        acc[6] = fmaxf(acc[6] + bb1.z, 0.f); acc[7] = fmaxf(acc[7] + bb1.w, 0.f);
        uint4 o;
        o.x = f2bf(acc[0]) | ((uint)f2bf(acc[1]) << 16);
        o.y = f2bf(acc[2]) | ((uint)f2bf(acc[3]) << 16);
        o.z = f2bf(acc[4]) | ((uint)f2bf(acc[5]) << 16);
        o.w = f2bf(acc[6]) | ((uint)f2bf(acc[7]) << 16);
        *(uint4*)&h1s[pass * 8 + grp][l * 8] = o;
    }
    __syncthreads();

    // phase B: xw2 tile [64 x 256] = h1s @ W2t^T
    int lane = t & 63, w = t >> 6;
    int wm = w >> 1, wn = w & 1;
    int l15 = lane & 15, l4 = lane >> 4;
    f32x4 acc[2][8];
    for (int i = 0; i < 2; i++)
        for (int j = 0; j < 8; j++) { f32x4 z = {0.f, 0.f, 0.f, 0.f}; acc[i][j] = z; }

    for (int kc = 0; kc < 8; kc++) {
        #pragma unroll
        for (int i = 0; i < 4; i++) {
            int linear = i * 256 + t;
            int col = linear >> 2, seg = linear & 3;
            *(uint4*)&Bs[col][seg * 8] = *(const uint4*)(W2t + (size_t)col * 256 + kc * 32 + seg * 8);
        }
        __syncthreads();
        bf16x8 af[2], bfr[8];
        #pragma unroll
        for (int mf = 0; mf < 2; mf++)
            af[mf] = *(const bf16x8*)&h1s[wm * 32 + mf * 16 + l15][kc * 32 + l4 * 8];
        #pragma unroll
        for (int nf = 0; nf < 8; nf++)
            bfr[nf] = *(const bf16x8*)&Bs[wn * 128 + nf * 16 + l15][l4 * 8];
        #pragma unroll
        for (int mf = 0; mf < 2; mf++)
            #pragma unroll
            for (int nf = 0; nf < 8; nf++)
                acc[mf][nf] = __builtin_amdgcn_mfma_f32_16x16x32_bf16(af[mf], bfr[nf], acc[mf][nf], 0, 0, 0);
        __syncthreads();
    }

    #pragma unroll
    for (int mf = 0; mf < 2; mf++)
        #pragma unroll
        for (int nf = 0; nf < 8; nf++)
            #pragma unroll
            for (int j = 0; j < 4; j++) {
                int r = brow + wm * 32 + mf * 16 + l4 * 4 + j;
                int c = wn * 128 + nf * 16 + l15;
                xw2[(size_t)r * 256 + c] = f2bf(acc[mf][nf][j]);
            }
}

// ---------- fused post: agg2(xw2)+b2+l2norm^2 -> rep f32 + rep8 ; y head from LDS ----------
__global__ __launch_bounds__(256) void post_kernel(const ushort* __restrict__ xw2,
                                                   const float* __restrict__ dinv,
                                                   const int* __restrict__ offsets,
                                                   const int* __restrict__ csr_src,
                                                   const float* __restrict__ b2,
                                                   const ushort* __restrict__ WyTb,
                                                   const float* __restrict__ by,
                                                   float* __restrict__ rep,
                                                   unsigned char* __restrict__ rep8,
                                                   float* __restrict__ y, int N) {
    __shared__ ushort reps[64][264];  // 33.8 KB
    __shared__ ushort ws[64][40];     // 5.2 KB per-chunk Wy
    int t = threadIdx.x;
    int brow = blockIdx.x * 64;
    int l = t & 31;
    int grp = t >> 5;

    // phase A: aggregate + norm, write rep f32 + rep8, keep bf16 row in LDS
    for (int pass = 0; pass < 8; pass++) {
        int v = brow + pass * 8 + grp;
        float dv = dinv[v];
        float acc[8] = {0, 0, 0, 0, 0, 0, 0, 0};
        uint4 q = *(const uint4*)(xw2 + (size_t)v * 256 + l * 8);
        fma8(acc, q, dv * dv);
        int beg = offsets[v], end = offsets[v + 1];
        int e = beg;
        for (; e + 2 <= end; e += 2) {
            int r0 = csr_src[e], r1 = csr_src[e + 1];
            float n0 = dinv[r0] * dv, n1 = dinv[r1] * dv;
            uint4 p0 = *(const uint4*)(xw2 + (size_t)r0 * 256 + l * 8);
            uint4 p1 = *(const uint4*)(xw2 + (size_t)r1 * 256 + l * 8);
            fma8(acc, p0, n0); fma8(acc, p1, n1);
        }
        if (e < end) {
            int r0 = csr_src[e];
            uint4 p0 = *(const uint4*)(xw2 + (size_t)r0 * 256 + l * 8);
            fma8(acc, p0, dinv[r0] * dv);
        }
        float4 bb0 = *(const float4*)(b2 + l * 8);
        float4 bb1 = *(const float4*)(b2 + l * 8 + 4);
        acc[0] += bb0.x; acc[1] += bb0.y; acc[2] += bb0.z; acc[3] += bb0.w;
        acc[4] += bb1.x; acc[5] += bb1.y; acc[6] += bb1.z; acc[7] += bb1.w;

        float ss = 0.f;
        #pragma unroll
        for (int i = 0; i < 8; i++) ss += acc[i] * acc[i];
        #pragma unroll
        for (int o = 1; o < 32; o <<= 1) ss += __shfl_xor(ss, o);
        float n1 = fmaxf(sqrtf(ss), 1e-12f);
        float i1 = 1.f / n1;
        float n2 = fmaxf(sqrtf(ss) * i1, 1e-12f);
        float sc = i1 / n2;
        #pragma unroll
        for (int i = 0; i < 8; i++) acc[i] *= sc;

        float4 o0, o1;
        o0.x = acc[0]; o0.y = acc[1]; o0.z = acc[2]; o0.w = acc[3];
        o1.x = acc[4]; o1.y = acc[5]; o1.z = acc[6]; o1.w = acc[7];
        *(float4*)(rep + (size_t)v * 256 + l * 8) = o0;
        *(float4*)(rep + (size_t)v * 256 + l * 8 + 4) = o1;
        uint4 ob;
        ob.x = f2bf(acc[0]) | ((uint)f2bf(acc[1]) << 16);
        ob.y = f2bf(acc[2]) | ((uint)f2bf(acc[3]) << 16);
        ob.z = f2bf(acc[4]) | ((uint)f2bf(acc[5]) << 16);
        ob.w = f2bf(acc[6]) | ((uint)f2bf(acc[7]) << 16);
        *(uint4*)&reps[pass * 8 + grp][l * 8] = ob;
        uint2 o8;
        o8.x = f2fp8(acc[0]) | (f2fp8(acc[1]) << 8) | (f2fp8(acc[2]) << 16) | (f2fp8(acc[3]) << 24);
        o8.y = f2fp8(acc[4]) | (f2fp8(acc[5]) << 8) | (f2fp8(acc[6]) << 16) | (f2fp8(acc[7]) << 24);
        *(uint2*)(rep8 + (size_t)v * 256 + l * 8) = o8;
    }
    __syncthreads();

    // phase B: y tile [64 x 40] = reps @ WyTb^T + by
    int lane = t & 63, w = t >> 6;
    int l15 = lane & 15, l4 = lane >> 4;
    f32x4 acc[4];
    for (int i = 0; i < 4; i++) { f32x4 z = {0.f, 0.f, 0.f, 0.f}; acc[i] = z; }

    for (int kc = 0; kc < 8; kc++) {
        {
            int n = t >> 2, seg = t & 3;
            *(uint4*)&ws[n][seg * 8] = *(const uint4*)(WyTb + (size_t)n * 256 + kc * 32 + seg * 8);
        }
        __syncthreads();
        bf16x8 af = *(const bf16x8*)&reps[w * 16 + l15][kc * 32 + l4 * 8];
        #pragma unroll
        for (int nf = 0; nf < 4; nf++) {
            bf16x8 bfr = *(const bf16x8*)&ws[nf * 16 + l15][l4 * 8];
            acc[nf] = __builtin_amdgcn_mfma_f32_16x16x32_bf16(af, bfr, acc[nf], 0, 0, 0);
        }
        __syncthreads();
    }

    #pragma unroll
    for (int nf = 0; nf < 4; nf++)
        #pragma unroll
        for (int j = 0; j < 4; j++) {
            int r = brow + w * 16 + l4 * 4 + j;
            int c = nf * 16 + l15;
            if (c < 40) y[(size_t)r * 40 + c] = acc[nf][j] + by[c];
        }
}

// ---------- loss tail: 16 lanes/edge, hw fp8 decode + ticket finalize ----------
__global__ __launch_bounds__(256) void loss_kernel(const unsigned char* __restrict__ rep8,
                                                   const int* __restrict__ pos_e,
                                                   const int* __restrict__ neg_e,
                                                   const float* __restrict__ simv,
                                                   const float* __restrict__ lsm,
                                                   float2* __restrict__ partials,
                                                   int* __restrict__ ticket,
                                                   float* __restrict__ out_loss,
                                                   int E, int N, int LB) {
    __shared__ float s_red[8];
    __shared__ int isLast;
    int t = threadIdx.x;
    int lb = blockIdx.x;
    int l16 = t & 15;
    int g = lb * 16 + (t >> 4);
    int ng = LB * 16;
    float tgt = lsm[0];
    float sse = 0.f, cntf = 0.f;
    for (int idx = g; idx < 2 * E; idx += ng) {
        bool is_pos = idx < E;
        int ei = is_pos ? idx : idx - E;
        const int* ep = is_pos ? pos_e : neg_e;
        int a = ep[ei];
        int b = ep[E + ei];
        if (a < b) {
            uint4 qa = *(const uint4*)(rep8 + (size_t)a * 256 + l16 * 16);
            uint4 qb = *(const uint4*)(rep8 + (size_t)b * 256 + l16 * 16);
            float d = fp8dot16(qa, qb);
            #pragma unroll
            for (int o = 1; o < 16; o <<= 1) d += __shfl_xor(d, o);
            float wr = fmaxf(d, 0.f);
            float term;
            if (is_pos) {
                float fsim = simv[ei];
                float p = fsim * 0.5f + wr * 0.5f;
                term = (p - tgt) * (p - tgt);
            } else {
                term = wr * wr;
            }
            sse += term;
            cntf += 1.f;
        }
    }
    sse += __shfl_xor(sse, 16); cntf += __shfl_xor(cntf, 16);
    sse += __shfl_xor(sse, 32); cntf += __shfl_xor(cntf, 32);
    if ((t & 63) == 0) { s_red[t >> 6] = sse; s_red[4 + (t >> 6)] = cntf; }
    __syncthreads();
    if (t == 0) {
        float2 pp;
        pp.x = s_red[0] + s_red[1] + s_red[2] + s_red[3];
        pp.y = s_red[4] + s_red[5] + s_red[6] + s_red[7];
        partials[lb] = pp;
        __threadfence();
        int prev = atomicAdd(ticket, 1);
        isLast = (prev == LB - 1) ? 1 : 0;
    }
    __syncthreads();
    if (isLast) {
        __threadfence();
        float fs = 0.f, fc = 0.f;
        for (int i = t; i < LB; i += 256) {
            float2 pp = partials[i];
            fs += pp.x; fc += pp.y;
        }
        #pragma unroll
        for (int o = 1; o < 64; o <<= 1) { fs += __shfl_xor(fs, o); fc += __shfl_xor(fc, o); }
        if ((t & 63) == 0) { s_red[t >> 6] = fs; s_red[4 + (t >> 6)] = fc; }
        __syncthreads();
        if (t == 0) {
            float S = s_red[0] + s_red[1] + s_red[2] + s_red[3];
            float Cc = s_red[4] + s_red[5] + s_red[6] + s_red[7];
            out_loss[0] = S * (float)N / Cc;
        }
    }
}

extern "C" void kernel_launch(void* const* d_in, const int* in_sizes, int n_in,
                              void* d_out, int out_size, void* d_ws, size_t ws_size,
                              hipStream_t stream) {
    const int*   edge  = (const int*)d_in[0];
    const int*   nedge = (const int*)d_in[1];
    const float* feat  = (const float*)d_in[2];
    const float* sim   = (const float*)d_in[3];
    const float* lsm   = (const float*)d_in[4];
    const float* W1    = (const float*)d_in[5];
    const float* b1    = (const float*)d_in[6];
    const float* W2    = (const float*)d_in[7];
    const float* b2    = (const float*)d_in[8];
    const float* Wy    = (const float*)d_in[9];
    const float* by    = (const float*)d_in[10];

    const int E = in_sizes[0] / 2;
    const int H = in_sizes[6];           // 256
    const int F = in_sizes[5] / H;       // 256
    const int N = in_sizes[2] / F;       // 16384

    const int* e_row = edge;
    const int* e_col = edge + E;

    const int LOSS_BLOCKS = 2048;
    const int NGB = 2 * (N / 128);       // 256 gemm1 blocks

    // workspace carve-up
    char* p = (char*)d_ws;
    int*    cnt      = (int*)p;    p += align256((size_t)N * 4);
    float*  dinv     = (float*)p;  p += align256((size_t)N * 4);
    int*    offsets  = (int*)p;    p += align256((size_t)(N + 1) * 4);
    int*    fillpos  = (int*)p;    p += align256((size_t)N * 4);
    int*    csr_src  = (int*)p;    p += align256((size_t)E * 4);
    ushort* W1t      = (ushort*)p; p += align256((size_t)F * H * 2);
    ushort* W2t      = (ushort*)p; p += align256((size_t)H * H * 2);
    ushort* WyTb     = (ushort*)p; p += align256((size_t)64 * H * 2);
    ushort* xw1      = (ushort*)p; p += align256((size_t)N * H * 2);
    ushort* xw2      = (ushort*)p; p += align256((size_t)N * H * 2);
    unsigned char* rep8 = (unsigned char*)p; p += align256((size_t)N * H);
    float*  simv     = (float*)p;  p += align256((size_t)E * 4);
    float2* partials = (float2*)p; p += align256((size_t)LOSS_BLOCKS * 8);
    int*    ticket   = (int*)p;    p += 256;

    float* rep  = (float*)d_out;
    float* loss = rep + (size_t)N * H;
    float* yout = loss + 1;

    hipMemsetAsync(cnt, 0, (size_t)N * 4, stream);

    // prep: count + weight conversions + sim prefetch + ticket zero
    {
        int total = 2 * E + 2 * H * H + 64 * H;
        prep_kernel<<<(total + 255) / 256, 256, 0, stream>>>(e_col, E, cnt, W1, W2, Wy,
                                                             W1t, W2t, WyTb, H, ticket,
                                                             e_row, sim, simv, N);
    }
    scan_offsets<<<1, 1024, 0, stream>>>(cnt, offsets, fillpos, dinv, N);

    // merged gemm1 + fill_csr
    fillgemm1_kernel<<<NGB + (E + 255) / 256, 256, 0, stream>>>(feat, W1t, xw1,
                                                                e_row, e_col, E,
                                                                fillpos, csr_src, NGB);

    // fused conv2: agg1 -> LDS -> gemm2 -> xw2
    conv2_fused_kernel<<<N / 64, 256, 0, stream>>>(xw1, dinv, offsets, csr_src, b1,
                                                   W2t, xw2, N);

    // fused post: agg2 + l2norm + rep/rep8 + y head
    post_kernel<<<N / 64, 256, 0, stream>>>(xw2, dinv, offsets, csr_src, b2,
                                            WyTb, by, rep, rep8, yout, N);

    // loss + finalize
    loss_kernel<<<LOSS_BLOCKS, 256, 0, stream>>>(rep8, edge, nedge, simv, lsm,
                                                 partials, ticket, loss, E, N, LOSS_BLOCKS);
}

// Round 9
// 263.223 us; speedup vs baseline: 1.5076x; 1.5076x over previous
//
#include <hip/hip_runtime.h>
#include <math.h>

typedef __attribute__((ext_vector_type(8))) short bf16x8;
typedef __attribute__((ext_vector_type(4))) float f32x4;
typedef __attribute__((ext_vector_type(2))) float f32x2;

static inline size_t align256(size_t x) { return (x + 255) & ~(size_t)255; }

__device__ inline ushort f2bf(float f) {
    uint u = __float_as_uint(f);
    u = (u + 0x7fffu + ((u >> 16) & 1u)) >> 16;
    return (ushort)u;
}
__device__ inline float bf2f(ushort b) { return __uint_as_float(((uint)b) << 16); }

// ---- manual OCP e4m3fn encode (|x| <= 1) ----
__device__ inline uint f2fp8(float x) {
    float ax = fabsf(x);
    uint s = (__float_as_uint(x) >> 31) << 7;
    if (ax < 0.015625f) {
        int q = (int)rintf(ax * 512.f);
        if (q == 8) return s | 0x08u;
        return s | (uint)q;
    }
    uint u = __float_as_uint(ax);
    u += 0x7ffffu + ((u >> 20) & 1u);
    int e8 = (int)(u >> 23) - 127;
    uint m = (u >> 20) & 7u;
    return s | ((uint)(e8 + 7) << 3) | m;
}

#if __has_builtin(__builtin_amdgcn_cvt_pk_f32_fp8)
__device__ inline float fp8dot16(uint4 qa, uint4 qb) {
    uint ua[4] = {qa.x, qa.y, qa.z, qa.w};
    uint ub[4] = {qb.x, qb.y, qb.z, qb.w};
    float s = 0.f;
    #pragma unroll
    for (int i = 0; i < 4; i++) {
        f32x2 a0 = __builtin_amdgcn_cvt_pk_f32_fp8(ua[i], false);
        f32x2 a1 = __builtin_amdgcn_cvt_pk_f32_fp8(ua[i], true);
        f32x2 b0 = __builtin_amdgcn_cvt_pk_f32_fp8(ub[i], false);
        f32x2 b1 = __builtin_amdgcn_cvt_pk_f32_fp8(ub[i], true);
        s += a0.x * b0.x + a0.y * b0.y + a1.x * b1.x + a1.y * b1.y;
    }
    return s;
}
#else
__device__ inline float fp8dec(uint b) {
    uint s = (b >> 7) & 1u, e = (b >> 3) & 0xfu, m = b & 7u;
    float dn = (float)(int)m * 0.001953125f;
    float nf = __uint_as_float((s << 31) | ((e + 120u) << 23) | (m << 20));
    float dv = s ? -dn : dn;
    return e ? nf : dv;
}
__device__ inline float fp8dot16(uint4 qa, uint4 qb) {
    uint ua[4] = {qa.x, qa.y, qa.z, qa.w};
    uint ub[4] = {qb.x, qb.y, qb.z, qb.w};
    float s = 0.f;
    #pragma unroll
    for (int i = 0; i < 4; i++)
        #pragma unroll
        for (int j = 0; j < 4; j++)
            s += fp8dec((ua[i] >> (8 * j)) & 0xffu) * fp8dec((ub[i] >> (8 * j)) & 0xffu);
    return s;
}
#endif

__device__ inline void fma8(float* acc, uint4 q, float s) {
    acc[0] += s * bf2f((ushort)(q.x & 0xffff)); acc[1] += s * bf2f((ushort)(q.x >> 16));
    acc[2] += s * bf2f((ushort)(q.y & 0xffff)); acc[3] += s * bf2f((ushort)(q.y >> 16));
    acc[4] += s * bf2f((ushort)(q.z & 0xffff)); acc[5] += s * bf2f((ushort)(q.z >> 16));
    acc[6] += s * bf2f((ushort)(q.w & 0xffff)); acc[7] += s * bf2f((ushort)(q.w >> 16));
}

// ---------- prep: count atomics + weight conversions + sim prefetch + ticket ----------
__global__ void prep_kernel(const int* __restrict__ e_col, int E, int* __restrict__ cnt,
                            const float* __restrict__ W1, const float* __restrict__ W2,
                            const float* __restrict__ Wy,
                            ushort* __restrict__ W1t, ushort* __restrict__ W2t,
                            ushort* __restrict__ WyTb, int H, int* __restrict__ ticket,
                            const int* __restrict__ pos_e, const float* __restrict__ sim,
                            float* __restrict__ simv, int N) {
    int i = blockIdx.x * blockDim.x + threadIdx.x;
    int HH = H * H;
    if (i == 0) *ticket = 0;
    if (i < E) {
        atomicAdd(&cnt[e_col[i]], 1);
    } else if (i < E + HH) {
        int j = i - E; int k = j / H, n = j % H;
        W1t[(size_t)n * H + k] = f2bf(W1[j]);
    } else if (i < E + 2 * HH) {
        int j = i - E - HH; int k = j / H, n = j % H;
        W2t[(size_t)n * H + k] = f2bf(W2[j]);
    } else if (i < E + 2 * HH + 64 * H) {
        int j = i - E - 2 * HH; int n = j / H, k = j % H;
        WyTb[j] = (n < 40) ? f2bf(Wy[(size_t)k * 40 + n]) : (ushort)0;
    } else if (i < E + 2 * HH + 64 * H + E) {
        int ei = i - (E + 2 * HH + 64 * H);
        int a = pos_e[ei], b = pos_e[E + ei];
        if (a < b) simv[ei] = sim[(size_t)a * N + b];
    }
}

// ---------- parallel scan (1024 threads, N = 16384) + dinv ----------
__global__ __launch_bounds__(1024) void scan_offsets(const int* __restrict__ cnt,
                                                     int* __restrict__ offsets,
                                                     int* __restrict__ fillpos,
                                                     float* __restrict__ dinv, int N) {
    __shared__ int wsum[16];
    int t = threadIdx.x;
    int lane = t & 63, w = t >> 6;
    int i0 = t * 16;
    int cl[16];
    #pragma unroll
    for (int j = 0; j < 4; j++) {
        int4 c = *(const int4*)(cnt + i0 + j * 4);
        cl[j * 4 + 0] = c.x; cl[j * 4 + 1] = c.y; cl[j * 4 + 2] = c.z; cl[j * 4 + 3] = c.w;
    }
    int s = 0;
    #pragma unroll
    for (int j = 0; j < 16; j++) s += cl[j];
    int x = s;
    #pragma unroll
    for (int o = 1; o < 64; o <<= 1) { int y = __shfl_up(x, o); if (lane >= o) x += y; }
    if (lane == 63) wsum[w] = x;
    __syncthreads();
    if (w == 0 && lane < 16) {
        int v = wsum[lane];
        #pragma unroll
        for (int o = 1; o < 16; o <<= 1) { int y = __shfl_up(v, o); if (lane >= o) v += y; }
        wsum[lane] = v;
    }
    __syncthreads();
    int wbase = (w == 0) ? 0 : wsum[w - 1];
    int off = wbase + x - s;
    #pragma unroll
    for (int j = 0; j < 16; j++) {
        int i = i0 + j;
        offsets[i] = off;
        fillpos[i] = off;
        dinv[i] = rsqrtf((float)(cl[j] + 1));
        off += cl[j];
    }
    if (t == 1023) offsets[N] = off;
}

// ---------- merged: gemm1 (blocks 0..NGB-1, f32 A staged->bf16) + fill_csr (rest) ----------
__global__ __launch_bounds__(256) void fillgemm1_kernel(const float* __restrict__ feat,
                                                        const ushort* __restrict__ W1t,
                                                        ushort* __restrict__ xw1,
                                                        const int* __restrict__ e_row,
                                                        const int* __restrict__ e_col, int E,
                                                        int* __restrict__ fillpos,
                                                        int* __restrict__ csr_src, int NGB) {
    __shared__ ushort As[128][40];
    __shared__ ushort Bs[128][40];
    int b = blockIdx.x;
    int t = threadIdx.x;

    if (b >= NGB) {
        int e = (b - NGB) * 256 + t;
        if (e < E) {
            int p = atomicAdd(&fillpos[e_col[e]], 1);
            csr_src[p] = e_row[e];
        }
        return;
    }

    const int K = 256;
    int lane = t & 63, w = t >> 6;
    int wm = w >> 1, wn = w & 1;
    int brow = (b >> 1) * 128, bcol = (b & 1) * 128;
    int l15 = lane & 15, l4 = lane >> 4;

    f32x4 acc[4][4];
    for (int i = 0; i < 4; i++)
        for (int j = 0; j < 4; j++) { f32x4 z = {0.f, 0.f, 0.f, 0.f}; acc[i][j] = z; }

    for (int k0 = 0; k0 < K; k0 += 32) {
        #pragma unroll
        for (int i = 0; i < 2; i++) {
            int idx = t + i * 256;
            int r = idx >> 2, seg = idx & 3;
            const float* ap = feat + (size_t)(brow + r) * K + k0 + seg * 8;
            float4 f0 = *(const float4*)ap;
            float4 f1 = *(const float4*)(ap + 4);
            uint4 va;
            va.x = f2bf(f0.x) | ((uint)f2bf(f0.y) << 16);
            va.y = f2bf(f0.z) | ((uint)f2bf(f0.w) << 16);
            va.z = f2bf(f1.x) | ((uint)f2bf(f1.y) << 16);
            va.w = f2bf(f1.z) | ((uint)f2bf(f1.w) << 16);
            *(uint4*)&As[r][seg * 8] = va;
            *(uint4*)&Bs[r][seg * 8] = *(const uint4*)(W1t + (size_t)(bcol + r) * K + k0 + seg * 8);
        }
        __syncthreads();
        bf16x8 af[4], bfr[4];
        #pragma unroll
        for (int mf = 0; mf < 4; mf++)
            af[mf] = *(const bf16x8*)&As[wm * 64 + mf * 16 + l15][l4 * 8];
        #pragma unroll
        for (int nf = 0; nf < 4; nf++)
            bfr[nf] = *(const bf16x8*)&Bs[wn * 64 + nf * 16 + l15][l4 * 8];
        #pragma unroll
        for (int mf = 0; mf < 4; mf++)
            #pragma unroll
            for (int nf = 0; nf < 4; nf++)
                acc[mf][nf] = __builtin_amdgcn_mfma_f32_16x16x32_bf16(af[mf], bfr[nf], acc[mf][nf], 0, 0, 0);
        __syncthreads();
    }

    #pragma unroll
    for (int mf = 0; mf < 4; mf++)
        #pragma unroll
        for (int nf = 0; nf < 4; nf++)
            #pragma unroll
            for (int j = 0; j < 4; j++) {
                int r = brow + wm * 64 + mf * 16 + l4 * 4 + j;
                int c = bcol + wn * 64 + nf * 16 + l15;
                xw1[(size_t)r * 256 + c] = f2bf(acc[mf][nf][j]);
            }
}

// ---------- bf16 MFMA GEMM (bf16 A) ----------
__global__ __launch_bounds__(256) void gemm_bf16_kernel(const ushort* __restrict__ A,
                                                        const ushort* __restrict__ Bt,
                                                        ushort* __restrict__ C, int M) {
    __shared__ ushort As[128][40];
    __shared__ ushort Bs[128][40];
    const int K = 256;
    int t = threadIdx.x;
    int lane = t & 63, w = t >> 6;
    int wm = w >> 1, wn = w & 1;
    int brow = blockIdx.y * 128, bcol = blockIdx.x * 128;
    int l15 = lane & 15, l4 = lane >> 4;

    f32x4 acc[4][4];
    for (int i = 0; i < 4; i++)
        for (int j = 0; j < 4; j++) { f32x4 z = {0.f, 0.f, 0.f, 0.f}; acc[i][j] = z; }

    for (int k0 = 0; k0 < K; k0 += 32) {
        #pragma unroll
        for (int i = 0; i < 2; i++) {
            int idx = t + i * 256;
            int r = idx >> 2, seg = idx & 3;
            *(uint4*)&As[r][seg * 8] = *(const uint4*)(A + (size_t)(brow + r) * K + k0 + seg * 8);
            *(uint4*)&Bs[r][seg * 8] = *(const uint4*)(Bt + (size_t)(bcol + r) * K + k0 + seg * 8);
        }
        __syncthreads();
        bf16x8 af[4], bfr[4];
        #pragma unroll
        for (int mf = 0; mf < 4; mf++)
            af[mf] = *(const bf16x8*)&As[wm * 64 + mf * 16 + l15][l4 * 8];
        #pragma unroll
        for (int nf = 0; nf < 4; nf++)
            bfr[nf] = *(const bf16x8*)&Bs[wn * 64 + nf * 16 + l15][l4 * 8];
        #pragma unroll
        for (int mf = 0; mf < 4; mf++)
            #pragma unroll
            for (int nf = 0; nf < 4; nf++)
                acc[mf][nf] = __builtin_amdgcn_mfma_f32_16x16x32_bf16(af[mf], bfr[nf], acc[mf][nf], 0, 0, 0);
        __syncthreads();
    }

    #pragma unroll
    for (int mf = 0; mf < 4; mf++)
        #pragma unroll
        for (int nf = 0; nf < 4; nf++)
            #pragma unroll
            for (int j = 0; j < 4; j++) {
                int r = brow + wm * 64 + mf * 16 + l4 * 4 + j;
                int c = bcol + wn * 64 + nf * 16 + l15;
                C[(size_t)r * 256 + c] = f2bf(acc[mf][nf][j]);
            }
}

// ---------- agg pass1: 32 lanes/node, unroll-4, relu, bf16 out ----------
__global__ __launch_bounds__(256) void gcn_agg1_kernel(const ushort* __restrict__ xw,
                                                       const float* __restrict__ dinv,
                                                       const int* __restrict__ offsets,
                                                       const int* __restrict__ csr_src,
                                                       const float* __restrict__ bias,
                                                       ushort* __restrict__ out_b, int N) {
    int t = threadIdx.x;
    int v = (blockIdx.x * blockDim.x + t) >> 5;
    int l = t & 31;
    if (v >= N) return;
    float dv = dinv[v];
    float acc[8] = {0, 0, 0, 0, 0, 0, 0, 0};
    uint4 q = *(const uint4*)(xw + (size_t)v * 256 + l * 8);
    fma8(acc, q, dv * dv);
    int beg = offsets[v], end = offsets[v + 1];
    int e = beg;
    for (; e + 4 <= end; e += 4) {
        int r0 = csr_src[e], r1 = csr_src[e + 1], r2 = csr_src[e + 2], r3 = csr_src[e + 3];
        float n0 = dinv[r0] * dv, n1 = dinv[r1] * dv, n2 = dinv[r2] * dv, n3 = dinv[r3] * dv;
        uint4 p0 = *(const uint4*)(xw + (size_t)r0 * 256 + l * 8);
        uint4 p1 = *(const uint4*)(xw + (size_t)r1 * 256 + l * 8);
        uint4 p2 = *(const uint4*)(xw + (size_t)r2 * 256 + l * 8);
        uint4 p3 = *(const uint4*)(xw + (size_t)r3 * 256 + l * 8);
        fma8(acc, p0, n0); fma8(acc, p1, n1); fma8(acc, p2, n2); fma8(acc, p3, n3);
    }
    for (; e < end; e++) {
        int r0 = csr_src[e];
        uint4 p0 = *(const uint4*)(xw + (size_t)r0 * 256 + l * 8);
        fma8(acc, p0, dinv[r0] * dv);
    }
    float4 b0 = *(const float4*)(bias + l * 8);
    float4 b1 = *(const float4*)(bias + l * 8 + 4);
    acc[0] = fmaxf(acc[0] + b0.x, 0.f); acc[1] = fmaxf(acc[1] + b0.y, 0.f);
    acc[2] = fmaxf(acc[2] + b0.z, 0.f); acc[3] = fmaxf(acc[3] + b0.w, 0.f);
    acc[4] = fmaxf(acc[4] + b1.x, 0.f); acc[5] = fmaxf(acc[5] + b1.y, 0.f);
    acc[6] = fmaxf(acc[6] + b1.z, 0.f); acc[7] = fmaxf(acc[7] + b1.w, 0.f);
    uint4 o;
    o.x = f2bf(acc[0]) | ((uint)f2bf(acc[1]) << 16);
    o.y = f2bf(acc[2]) | ((uint)f2bf(acc[3]) << 16);
    o.z = f2bf(acc[4]) | ((uint)f2bf(acc[5]) << 16);
    o.w = f2bf(acc[6]) | ((uint)f2bf(acc[7]) << 16);
    *(uint4*)(out_b + (size_t)v * 256 + l * 8) = o;
}

// ---------- agg pass2 + bias + double l2norm; writes rep f32, repb bf16, rep8 fp8 ----------
__global__ __launch_bounds__(256) void gcn_agg2_kernel(const ushort* __restrict__ xw,
                                                       const float* __restrict__ dinv,
                                                       const int* __restrict__ offsets,
                                                       const int* __restrict__ csr_src,
                                                       const float* __restrict__ b2,
                                                       float* __restrict__ rep,
                                                       ushort* __restrict__ repb,
                                                       unsigned char* __restrict__ rep8, int N) {
    int t = threadIdx.x;
    int v = (blockIdx.x * blockDim.x + t) >> 5;
    int l = t & 31;
    if (v >= N) return;
    float dv = dinv[v];
    float acc[8] = {0, 0, 0, 0, 0, 0, 0, 0};
    uint4 q = *(const uint4*)(xw + (size_t)v * 256 + l * 8);
    fma8(acc, q, dv * dv);
    int beg = offsets[v], end = offsets[v + 1];
    int e = beg;
    for (; e + 4 <= end; e += 4) {
        int r0 = csr_src[e], r1 = csr_src[e + 1], r2 = csr_src[e + 2], r3 = csr_src[e + 3];
        float n0 = dinv[r0] * dv, n1 = dinv[r1] * dv, n2 = dinv[r2] * dv, n3 = dinv[r3] * dv;
        uint4 p0 = *(const uint4*)(xw + (size_t)r0 * 256 + l * 8);
        uint4 p1 = *(const uint4*)(xw + (size_t)r1 * 256 + l * 8);
        uint4 p2 = *(const uint4*)(xw + (size_t)r2 * 256 + l * 8);
        uint4 p3 = *(const uint4*)(xw + (size_t)r3 * 256 + l * 8);
        fma8(acc, p0, n0); fma8(acc, p1, n1); fma8(acc, p2, n2); fma8(acc, p3, n3);
    }
    for (; e < end; e++) {
        int r0 = csr_src[e];
        uint4 p0 = *(const uint4*)(xw + (size_t)r0 * 256 + l * 8);
        fma8(acc, p0, dinv[r0] * dv);
    }
    float4 b0 = *(const float4*)(b2 + l * 8);
    float4 b1 = *(const float4*)(b2 + l * 8 + 4);
    acc[0] += b0.x; acc[1] += b0.y; acc[2] += b0.z; acc[3] += b0.w;
    acc[4] += b1.x; acc[5] += b1.y; acc[6] += b1.z; acc[7] += b1.w;

    float ss = 0.f;
    #pragma unroll
    for (int i = 0; i < 8; i++) ss += acc[i] * acc[i];
    #pragma unroll
    for (int o = 1; o < 32; o <<= 1) ss += __shfl_xor(ss, o);
    float n1 = fmaxf(sqrtf(ss), 1e-12f);
    float i1 = 1.f / n1;
    float n2 = fmaxf(sqrtf(ss) * i1, 1e-12f);
    float sc = i1 / n2;
    #pragma unroll
    for (int i = 0; i < 8; i++) acc[i] *= sc;

    float4 o0, o1;
    o0.x = acc[0]; o0.y = acc[1]; o0.z = acc[2]; o0.w = acc[3];
    o1.x = acc[4]; o1.y = acc[5]; o1.z = acc[6]; o1.w = acc[7];
    *(float4*)(rep + (size_t)v * 256 + l * 8) = o0;
    *(float4*)(rep + (size_t)v * 256 + l * 8 + 4) = o1;
    uint4 ob;
    ob.x = f2bf(acc[0]) | ((uint)f2bf(acc[1]) << 16);
    ob.y = f2bf(acc[2]) | ((uint)f2bf(acc[3]) << 16);
    ob.z = f2bf(acc[4]) | ((uint)f2bf(acc[5]) << 16);
    ob.w = f2bf(acc[6]) | ((uint)f2bf(acc[7]) << 16);
    *(uint4*)(repb + (size_t)v * 256 + l * 8) = ob;
    uint2 o8;
    o8.x = f2fp8(acc[0]) | (f2fp8(acc[1]) << 8) | (f2fp8(acc[2]) << 16) | (f2fp8(acc[3]) << 24);
    o8.y = f2fp8(acc[4]) | (f2fp8(acc[5]) << 8) | (f2fp8(acc[6]) << 16) | (f2fp8(acc[7]) << 24);
    *(uint2*)(rep8 + (size_t)v * 256 + l * 8) = o8;
}

// ---------- merged tail: gemm_y (blocks 0..NYB) + loss (rest) + ticket finalize ----------
__global__ __launch_bounds__(256) void tail_kernel(const ushort* __restrict__ repb,
                                                   const ushort* __restrict__ WyTb,
                                                   const float* __restrict__ by,
                                                   float* __restrict__ y,
                                                   const unsigned char* __restrict__ rep8,
                                                   const int* __restrict__ pos_e,
                                                   const int* __restrict__ neg_e,
                                                   const float* __restrict__ simv,
                                                   const float* __restrict__ lsm,
                                                   float2* __restrict__ partials,
                                                   int* __restrict__ ticket,
                                                   float* __restrict__ out_loss,
                                                   int E, int N, int NYB, int LB) {
    __shared__ ushort As[64][40];
    __shared__ ushort Bs[64][40];
    __shared__ float s_red[8];
    __shared__ int isLast;
    int t = threadIdx.x;

    if ((int)blockIdx.x < NYB) {
        const int K = 256;
        int lane = t & 63, w = t >> 6;
        int brow = blockIdx.x * 64;
        int l15 = lane & 15, l4 = lane >> 4;
        f32x4 acc[4];
        for (int i = 0; i < 4; i++) { f32x4 z = {0.f, 0.f, 0.f, 0.f}; acc[i] = z; }
        for (int k0 = 0; k0 < K; k0 += 32) {
            int r = t >> 2, seg = t & 3;
            *(uint4*)&As[r][seg * 8] = *(const uint4*)(repb + (size_t)(brow + r) * K + k0 + seg * 8);
            *(uint4*)&Bs[r][seg * 8] = *(const uint4*)(WyTb + (size_t)r * K + k0 + seg * 8);
            __syncthreads();
            bf16x8 af = *(const bf16x8*)&As[w * 16 + l15][l4 * 8];
            #pragma unroll
            for (int nf = 0; nf < 4; nf++) {
                bf16x8 bfr = *(const bf16x8*)&Bs[nf * 16 + l15][l4 * 8];
                acc[nf] = __builtin_amdgcn_mfma_f32_16x16x32_bf16(af, bfr, acc[nf], 0, 0, 0);
            }
            __syncthreads();
        }
        #pragma unroll
        for (int nf = 0; nf < 4; nf++)
            #pragma unroll
            for (int j = 0; j < 4; j++) {
                int r = brow + w * 16 + l4 * 4 + j;
                int c = nf * 16 + l15;
                if (c < 40) y[(size_t)r * 40 + c] = acc[nf][j] + by[c];
            }
        return;
    }

    // ---- loss: 16 lanes/edge, hw fp8 decode, prefetched sim ----
    int lb = (int)blockIdx.x - NYB;
    int l16 = t & 15;
    int g = lb * 16 + (t >> 4);
    int ng = LB * 16;
    float tgt = lsm[0];
    float sse = 0.f, cntf = 0.f;
    for (int idx = g; idx < 2 * E; idx += ng) {
        bool is_pos = idx < E;
        int ei = is_pos ? idx : idx - E;
        const int* ep = is_pos ? pos_e : neg_e;
        int a = ep[ei];
        int b = ep[E + ei];
        if (a < b) {
            uint4 qa = *(const uint4*)(rep8 + (size_t)a * 256 + l16 * 16);
            uint4 qb = *(const uint4*)(rep8 + (size_t)b * 256 + l16 * 16);
            float d = fp8dot16(qa, qb);
            #pragma unroll
            for (int o = 1; o < 16; o <<= 1) d += __shfl_xor(d, o);
            float wr = fmaxf(d, 0.f);
            float term;
            if (is_pos) {
                float fsim = simv[ei];
                float p = fsim * 0.5f + wr * 0.5f;
                term = (p - tgt) * (p - tgt);
            } else {
                term = wr * wr;
            }
            sse += term;
            cntf += 1.f;
        }
    }
    sse += __shfl_xor(sse, 16); cntf += __shfl_xor(cntf, 16);
    sse += __shfl_xor(sse, 32); cntf += __shfl_xor(cntf, 32);
    if ((t & 63) == 0) { s_red[t >> 6] = sse; s_red[4 + (t >> 6)] = cntf; }
    __syncthreads();
    if (t == 0) {
        float2 pp;
        pp.x = s_red[0] + s_red[1] + s_red[2] + s_red[3];
        pp.y = s_red[4] + s_red[5] + s_red[6] + s_red[7];
        partials[lb] = pp;
        __threadfence();
        int prev = atomicAdd(ticket, 1);
        isLast = (prev == LB - 1) ? 1 : 0;
    }
    __syncthreads();
    if (isLast) {
        __threadfence();
        float fs = 0.f, fc = 0.f;
        for (int i = t; i < LB; i += 256) {
            float2 pp = partials[i];
            fs += pp.x; fc += pp.y;
        }
        #pragma unroll
        for (int o = 1; o < 64; o <<= 1) { fs += __shfl_xor(fs, o); fc += __shfl_xor(fc, o); }
        if ((t & 63) == 0) { s_red[t >> 6] = fs; s_red[4 + (t >> 6)] = fc; }
        __syncthreads();
        if (t == 0) {
            float S = s_red[0] + s_red[1] + s_red[2] + s_red[3];
            float Cc = s_red[4] + s_red[5] + s_red[6] + s_red[7];
            out_loss[0] = S * (float)N / Cc;
        }
    }
}

extern "C" void kernel_launch(void* const* d_in, const int* in_sizes, int n_in,
                              void* d_out, int out_size, void* d_ws, size_t ws_size,
                              hipStream_t stream) {
    const int*   edge  = (const int*)d_in[0];
    const int*   nedge = (const int*)d_in[1];
    const float* feat  = (const float*)d_in[2];
    const float* sim   = (const float*)d_in[3];
    const float* lsm   = (const float*)d_in[4];
    const float* W1    = (const float*)d_in[5];
    const float* b1    = (const float*)d_in[6];
    const float* W2    = (const float*)d_in[7];
    const float* b2    = (const float*)d_in[8];
    const float* Wy    = (const float*)d_in[9];
    const float* by    = (const float*)d_in[10];

    const int E = in_sizes[0] / 2;
    const int H = in_sizes[6];           // 256
    const int F = in_sizes[5] / H;       // 256
    const int N = in_sizes[2] / F;       // 16384

    const int* e_row = edge;
    const int* e_col = edge + E;

    const int LOSS_BLOCKS = 2048;
    const int NYB = N / 64;              // 256
    const int NGB = 2 * (N / 128);       // 256 gemm1 blocks

    // workspace carve-up
    char* p = (char*)d_ws;
    int*    cnt      = (int*)p;    p += align256((size_t)N * 4);
    float*  dinv     = (float*)p;  p += align256((size_t)N * 4);
    int*    offsets  = (int*)p;    p += align256((size_t)(N + 1) * 4);
    int*    fillpos  = (int*)p;    p += align256((size_t)N * 4);
    int*    csr_src  = (int*)p;    p += align256((size_t)E * 4);
    ushort* W1t      = (ushort*)p; p += align256((size_t)F * H * 2);
    ushort* W2t      = (ushort*)p; p += align256((size_t)H * H * 2);
    ushort* WyTb     = (ushort*)p; p += align256((size_t)64 * H * 2);
    ushort* h1b      = (ushort*)p; p += align256((size_t)N * H * 2);
    ushort* xwb      = (ushort*)p; p += align256((size_t)N * H * 2);
    ushort* repb     = (ushort*)p; p += align256((size_t)N * H * 2);
    unsigned char* rep8 = (unsigned char*)p; p += align256((size_t)N * H);
    float*  simv     = (float*)p;  p += align256((size_t)E * 4);
    float2* partials = (float2*)p; p += align256((size_t)LOSS_BLOCKS * 8);
    int*    ticket   = (int*)p;    p += 256;

    float* rep  = (float*)d_out;
    float* loss = rep + (size_t)N * H;
    float* yout = loss + 1;

    hipMemsetAsync(cnt, 0, (size_t)N * 4, stream);

    // prep: count + weight conversions + sim prefetch + ticket zero
    {
        int total = 2 * E + 2 * H * H + 64 * H;
        prep_kernel<<<(total + 255) / 256, 256, 0, stream>>>(e_col, E, cnt, W1, W2, Wy,
                                                             W1t, W2t, WyTb, H, ticket,
                                                             e_row, sim, simv, N);
    }
    scan_offsets<<<1, 1024, 0, stream>>>(cnt, offsets, fillpos, dinv, N);

    // merged gemm1 (xw1 = bf16(feat)@W1) + fill_csr
    fillgemm1_kernel<<<NGB + (E + 255) / 256, 256, 0, stream>>>(feat, W1t, xwb,
                                                                e_row, e_col, E,
                                                                fillpos, csr_src, NGB);

    // agg1 (2048 blocks, latency-hiding TLP)
    gcn_agg1_kernel<<<N * 32 / 256, 256, 0, stream>>>(xwb, dinv, offsets, csr_src, b1, h1b, N);

    // conv2 GEMM
    {
        dim3 grid(2, N / 128);
        gemm_bf16_kernel<<<grid, 256, 0, stream>>>(h1b, W2t, xwb, N);
    }
    // agg2 + l2norm
    gcn_agg2_kernel<<<N * 32 / 256, 256, 0, stream>>>(xwb, dinv, offsets, csr_src, b2,
                                                      rep, repb, rep8, N);

    // merged y-head + loss + finalize
    tail_kernel<<<NYB + LOSS_BLOCKS, 256, 0, stream>>>(repb, WyTb, by, yout, rep8,
                                                       edge, nedge, simv, lsm, partials,
                                                       ticket, loss, E, N, NYB, LOSS_BLOCKS);
}